// Round 3
// baseline (33.771 us; speedup 1.0000x reference)
//
#include <hip/hip_runtime.h>

// ROI Align (B=8, H=32, W=32, C=256 NHWC fp32; R=128 ROIs/batch; 7x7 out, 2x2 samples).
//
// Round 3: occupancy fix. One block per (ROI, 16-channel tile):
//   - LDS tile = 16x16 pixels x 16 channels = 16 KB -> 8 blocks/CU (32 waves, 100%).
//   - Stage via global_load_lds width 16 (linear LDS dest, per-lane global src).
//   - Each thread computes exactly ONE output cell x 4 channels (float4).
// Box span < 13.94 px guarantees all bilinear taps fall in the 16x16 rect
// (staging clamps rows/cols at 31, matching the reference's index clamping).
// XCD swizzle: batch == XCD so each XCD's L2 holds only its 1 MB fm slice.

#define NB 8
#define NH 32
#define NW 32
#define NR 128

typedef const __attribute__((address_space(1))) unsigned int* gptr_t;
typedef __attribute__((address_space(3))) unsigned int* lptr_t;

__device__ __forceinline__ float4 lerp4(float4 a, float4 b, float w) {
    float4 r;
    r.x = a.x + (b.x - a.x) * w;
    r.y = a.y + (b.y - a.y) * w;
    r.z = a.z + (b.z - a.z) * w;
    r.w = a.w + (b.w - a.w) * w;
    return r;
}

__global__ __launch_bounds__(256) void roi_align_lds16(
    const float* __restrict__ fm,
    const float* __restrict__ boxes,
    float* __restrict__ out)
{
    __shared__ float4 tile[16 * 16 * 4];   // [py][px][c4of4] = 16 KB

    // grid = 16384 blocks = 1024 ROIs x 16 channel-tiles.
    // Swizzle: XCD (= blockIdx % 8, round-robin) == batch index.
    int bid = blockIdx.x;
    int newid = (bid & 7) * 2048 + (bid >> 3);
    int n = newid >> 4;          // ROI index 0..1023 (b*128 + r)
    int ctile = newid & 15;      // 16-channel tile (4 float4)
    int b = n >> 7;
    int t = threadIdx.x;

    // Box math — identical to the verified round-1/2 kernels.
    float bx0 = boxes[n * 4 + 0] * (1.0f / 31.0f);
    float by0 = boxes[n * 4 + 1] * (1.0f / 31.0f);
    float bx1 = boxes[n * 4 + 2] * (1.0f / 31.0f);
    float by1 = boxes[n * 4 + 3] * (1.0f / 31.0f);
    float x1 = fmaxf(bx0, 0.0f), y1 = fmaxf(by0, 0.0f);
    float x2 = fminf(bx1, 1.0f), y2 = fminf(by1, 1.0f);
    float bin_h = (y2 - y1) / 7.0f;
    float bin_w = (x2 - x1) / 7.0f;
    float gy1 = y1 + 0.25f * bin_h;
    float gx1 = x1 + 0.25f * bin_w;
    float gy2 = y2 - 0.25f * bin_h;
    float gx2 = x2 - 0.25f * bin_w;
    float basey = gy1 * 31.0f;
    float basex = gx1 * 31.0f;
    float stepy = (gy2 - gy1) * (31.0f / 13.0f);
    float stepx = (gx2 - gx1) * (31.0f / 13.0f);

    int ylo = (int)floorf(basey);
    int xlo = (int)floorf(basex);

    // ---- stage 16x16 rect x 16 channels into LDS (4 float4 per thread) ----
    const float4* fm4 = (const float4*)fm;
    #pragma unroll
    for (int iter = 0; iter < 4; ++iter) {
        int idx = iter * 256 + t;          // flat float4 index into tile
        int py = idx >> 6;                 // 64 float4 per pixel row
        int px = (idx >> 2) & 15;
        int lc = idx & 3;
        int yg = min(ylo + py, NH - 1);
        int xg = min(xlo + px, NW - 1);
        const float4* src = fm4 + (((b * NH + yg) * NW + xg) * 64 + ctile * 4 + lc);
        __builtin_amdgcn_global_load_lds((gptr_t)src, (lptr_t)&tile[idx], 16, 0, 0);
    }
    __syncthreads();

    // ---- compute: one cell x one float4 per thread ----
    int cell = t >> 2;                     // 0..63 (49 used)
    int lc = t & 3;
    if (cell < 49) {
        int oy = (cell * 37) >> 8;         // cell/7 for 0..48
        int ox = cell - oy * 7;
        float4 acc = make_float4(0.f, 0.f, 0.f, 0.f);
        #pragma unroll
        for (int sy = 0; sy < 2; ++sy) {
            float ysf = basey + (float)(2 * oy + sy) * stepy;
            float y0f = floorf(ysf);
            float wy  = ysf - y0f;
            int y0c = (int)y0f;
            int y0i = min(max(y0c, 0), NH - 1);
            int y1i = min(y0i + 1, NH - 1);
            int ry0 = (y0i - ylo) << 4;    // *16 px per row
            int ry1 = (y1i - ylo) << 4;
            #pragma unroll
            for (int sx = 0; sx < 2; ++sx) {
                float xsf = basex + (float)(2 * ox + sx) * stepx;
                float x0f = floorf(xsf);
                float wx  = xsf - x0f;
                int x0c = (int)x0f;
                int x0i = min(max(x0c, 0), NW - 1);
                int x1i = min(x0i + 1, NW - 1);
                int rx0 = x0i - xlo;
                int rx1 = x1i - xlo;
                float4 v00 = tile[((ry0 + rx0) << 2) + lc];
                float4 v01 = tile[((ry0 + rx1) << 2) + lc];
                float4 v10 = tile[((ry1 + rx0) << 2) + lc];
                float4 v11 = tile[((ry1 + rx1) << 2) + lc];
                float4 top = lerp4(v00, v01, wx);
                float4 bot = lerp4(v10, v11, wx);
                float4 val = lerp4(top, bot, wy);
                acc.x += val.x; acc.y += val.y; acc.z += val.z; acc.w += val.w;
            }
        }
        acc.x *= 0.25f; acc.y *= 0.25f; acc.z *= 0.25f; acc.w *= 0.25f;
        float4* out4 = (float4*)out;
        out4[(n * 49 + cell) * 64 + ctile * 4 + lc] = acc;
    }
}

extern "C" void kernel_launch(void* const* d_in, const int* in_sizes, int n_in,
                              void* d_out, int out_size, void* d_ws, size_t ws_size,
                              hipStream_t stream) {
    const float* fm    = (const float*)d_in[0];
    const float* boxes = (const float*)d_in[1];
    float* out = (float*)d_out;

    int blocks = NB * NR * 16;   // 16384: 1024 ROIs x 16 channel tiles
    roi_align_lds16<<<blocks, 256, 0, stream>>>(fm, boxes, out);
}

// Round 5
// 28.670 us; speedup vs baseline: 1.1779x; 1.1779x over previous
//
#include <hip/hip_runtime.h>

// ROI Align (B=8, H=32, W=32, C=256 NHWC fp32; R=128 ROIs; 7x7 out, 2x2 samples).
//
// Round 5: tap-dedup, corrected. stepx/stepy <= 15/14 ~ 1.071 (NOT < 1), so
// consecutive sample floors differ by 0..2 and dy in {0,1,2}. Use a rolling
// 2-col x 4-row register window over the 14 x-samples of one (ROI, oy) row.
//   - wave = (ROI, oy); lane = channel-float4 (64 lanes = 256 ch) -> every tap
//     is one coalesced 1 KB load, control flow wave-uniform (readfirstlane).
//   - rows f0..f0+3 (clamped) cover sy0 (rows 0,1) and sy1 (rows dy,dy+1).
//   - per sample: shift window by s=0/1/2 cols (uniform branch), 4 h-lerps,
//     2 v-lerps (row pair for sy1 selected by uniform dy).
// Gather traffic ~320 MB (vs 822 MB for independent taps), XCD-local L2.

#define NB 8
#define NH 32
#define NW 32
#define NR 128

__device__ __forceinline__ float4 lerp4(float4 a, float4 b, float w) {
    float4 r;
    r.x = a.x + (b.x - a.x) * w;
    r.y = a.y + (b.y - a.y) * w;
    r.z = a.z + (b.z - a.z) * w;
    r.w = a.w + (b.w - a.w) * w;
    return r;
}

__global__ __launch_bounds__(256) void roi_align_win4(
    const float* __restrict__ fm,
    const float* __restrict__ boxes,
    float* __restrict__ out)
{
    int bid = blockIdx.x;
    int newbid = (bid & 7) * 224 + (bid >> 3);   // XCD -> batch locality
    int t = threadIdx.x;
    int lane = t & 63;                           // channel float4 group
    int g = newbid * 4 + (t >> 6);               // wave id 0..7167 = (n, oy)
    int n = (int)(((unsigned)g * 9363u) >> 16);  // g / 7 (exact for g < 7168)
    int oy = g - n * 7;
    int b = n >> 7;

    // Box math — identical to the verified round-1..3 kernels.
    float bx0 = boxes[n * 4 + 0] * (1.0f / 31.0f);
    float by0 = boxes[n * 4 + 1] * (1.0f / 31.0f);
    float bx1 = boxes[n * 4 + 2] * (1.0f / 31.0f);
    float by1 = boxes[n * 4 + 3] * (1.0f / 31.0f);
    float x1 = fmaxf(bx0, 0.0f), y1 = fmaxf(by0, 0.0f);
    float x2 = fminf(bx1, 1.0f), y2 = fminf(by1, 1.0f);
    float bin_h = (y2 - y1) / 7.0f;
    float bin_w = (x2 - x1) / 7.0f;
    float gy1 = y1 + 0.25f * bin_h;
    float gx1 = x1 + 0.25f * bin_w;
    float gy2 = y2 - 0.25f * bin_h;
    float gx2 = x2 - 0.25f * bin_w;
    float basey = gy1 * 31.0f;
    float basex = gx1 * 31.0f;
    float stepy = (gy2 - gy1) * (31.0f / 13.0f);
    float stepx = (gx2 - gx1) * (31.0f / 13.0f);

    // Row geometry for this oy (fixed across all 14 x-samples).
    float ysf0 = basey + (float)(2 * oy) * stepy;
    float ysf1 = basey + (float)(2 * oy + 1) * stepy;
    float f0f = floorf(ysf0);
    float f1f = floorf(ysf1);
    float wy0 = ysf0 - f0f;
    float wy1 = ysf1 - f1f;
    int f0 = (int)f0f;                                        // >= 0
    int dy = __builtin_amdgcn_readfirstlane((int)f1f - f0);   // 0, 1, or 2

    const float4* fm4 = (const float4*)fm;
    const float4* basep = fm4 + (size_t)b * (NH * NW * 64) + lane;
    int ro0 = (min(f0,     NH - 1) * NW) << 6;
    int ro1 = (min(f0 + 1, NH - 1) * NW) << 6;
    int ro2 = (min(f0 + 2, NH - 1) * NW) << 6;
    int ro3 = (min(f0 + 3, NH - 1) * NW) << 6;

#define LOADCOL(R0, R1, R2, R3, cidx) do {         \
        int xo_ = (min((cidx), NW - 1)) << 6;      \
        R0 = basep[ro0 + xo_];                     \
        R1 = basep[ro1 + xo_];                     \
        R2 = basep[ro2 + xo_];                     \
        R3 = basep[ro3 + xo_];                     \
    } while (0)

    // Rolling window: cols (cl, cl+1) x rows 0..3.
    int cl = __builtin_amdgcn_readfirstlane((int)floorf(basex));
    float4 a0, a1, a2, a3, b0, b1, b2, b3;
    LOADCOL(a0, a1, a2, a3, cl);
    LOADCOL(b0, b1, b2, b3, cl + 1);

    float4* out4 = (float4*)out;
    int obase = (n * 49 + oy * 7) * 64 + lane;

    float4 acc = make_float4(0.f, 0.f, 0.f, 0.f);
    #pragma unroll
    for (int is = 0; is < 14; ++is) {
        float xsf = basex + (float)is * stepx;
        float gf = floorf(xsf);
        float wx = xsf - gf;
        int gi = __builtin_amdgcn_readfirstlane((int)gf);
        int s = gi - cl;                          // 0, 1, or 2 (monotone)
        if (s == 1) {
            a0 = b0; a1 = b1; a2 = b2; a3 = b3;
            LOADCOL(b0, b1, b2, b3, gi + 1);
        } else if (s == 2) {
            LOADCOL(a0, a1, a2, a3, gi);
            LOADCOL(b0, b1, b2, b3, gi + 1);
        }
        cl = gi;

        // Horizontal lerps for the 4 cached rows.
        float4 h0 = lerp4(a0, b0, wx);
        float4 h1 = lerp4(a1, b1, wx);
        float4 h2 = lerp4(a2, b2, wx);
        float4 h3 = lerp4(a3, b3, wx);
        // sy0 uses rows (0,1); sy1 uses rows (dy, dy+1) — dy wave-uniform.
        float4 slo = lerp4(h0, h1, wy0);
        float4 hA = (dy == 0) ? h0 : ((dy == 1) ? h1 : h2);
        float4 hB = (dy == 0) ? h1 : ((dy == 1) ? h2 : h3);
        float4 shi = lerp4(hA, hB, wy1);

        acc.x += slo.x + shi.x;
        acc.y += slo.y + shi.y;
        acc.z += slo.z + shi.z;
        acc.w += slo.w + shi.w;

        if (is & 1) {
            float4 r;
            r.x = acc.x * 0.25f; r.y = acc.y * 0.25f;
            r.z = acc.z * 0.25f; r.w = acc.w * 0.25f;
            out4[obase + ((is >> 1) << 6)] = r;
            acc = make_float4(0.f, 0.f, 0.f, 0.f);
        }
    }
#undef LOADCOL
}

extern "C" void kernel_launch(void* const* d_in, const int* in_sizes, int n_in,
                              void* d_out, int out_size, void* d_ws, size_t ws_size,
                              hipStream_t stream) {
    const float* fm    = (const float*)d_in[0];
    const float* boxes = (const float*)d_in[1];
    float* out = (float*)d_out;

    // 7168 waves = 1024 ROIs x 7 oy-rows; 4 waves/block -> 1792 blocks.
    roi_align_win4<<<1792, 256, 0, stream>>>(fm, boxes, out);
}

// Round 6
// 21.839 us; speedup vs baseline: 1.5463x; 1.3128x over previous
//
#include <hip/hip_runtime.h>

// ROI Align (B=8, H=32, W=32, C=256 NHWC fp32; R=128 ROIs; 7x7 out, 2x2 samples).
//
// Round 6: column-major separable structure.
//  - wave = (ROI, oy); lane = channel-float4 (64 lanes = 256 ch).
//  - Bilinear is separable and both y-samples share every x-position, so each
//    column's 2-4 rows reduce ONCE to vsum[col] = lerp(r0,r1,wy0) +
//    lerp(r_dy,r_dy+1,wy1). Samples then need one h-lerp each.
//  - Outer loop walks 16 statically-enumerated columns (shift = exactly 1 per
//    iter); inner uniform while consumes the 0-4 samples whose floor == col.
//    All load addresses are independent of the sample stream -> full MLP.
//  - dy in {0,1,2} is wave-uniform: template-specialized so dy<=1 loads 2-3
//    rows per column instead of 4.
// XCD swizzle: blockIdx%8 == batch -> each XCD's L2 holds its 1 MB fm slice.

#define NB 8
#define NH 32
#define NW 32
#define NR 128

__device__ __forceinline__ float4 lerp4(float4 a, float4 b, float w) {
    float4 r;
    r.x = a.x + (b.x - a.x) * w;
    r.y = a.y + (b.y - a.y) * w;
    r.z = a.z + (b.z - a.z) * w;
    r.w = a.w + (b.w - a.w) * w;
    return r;
}

template<int DY>
__device__ __forceinline__ void roi_row_proc(
    const float4* __restrict__ basep,     // fm4 + batch offset + lane
    int ro0, int ro1, int ro2, int ro3,   // row offsets (float4 units)
    int xlo, float basex, float stepx,
    float wy0, float wy1,
    float4* __restrict__ outp)            // out4 + (n*49+oy*7)*64 + lane
{
    // Vertical reduction of one column (2..4 loads, one vsum).
    auto vsum_col = [&](int cidx) -> float4 {
        int xo = (min(cidx, NW - 1)) << 6;
        float4 r0 = basep[ro0 + xo];
        float4 r1 = basep[ro1 + xo];
        float4 lo = lerp4(r0, r1, wy0);
        float4 hi;
        if constexpr (DY == 0) {
            hi = lerp4(r0, r1, wy1);
        } else if constexpr (DY == 1) {
            float4 r2 = basep[ro2 + xo];
            hi = lerp4(r1, r2, wy1);
        } else {
            float4 r2 = basep[ro2 + xo];
            float4 r3 = basep[ro3 + xo];
            hi = lerp4(r2, r3, wy1);
        }
        float4 v;
        v.x = lo.x + hi.x; v.y = lo.y + hi.y;
        v.z = lo.z + hi.z; v.w = lo.w + hi.w;
        return v;
    };

    float4 va = vsum_col(xlo);
    int s = 0;
    float xsf = basex;
    float gf = floorf(xsf);
    int gn = __builtin_amdgcn_readfirstlane((int)gf) - xlo;   // == 0
    float wx = xsf - gf;
    float4 acc = make_float4(0.f, 0.f, 0.f, 0.f);

    #pragma unroll
    for (int ci = 0; ci < 15; ++ci) {
        float4 vb = vsum_col(xlo + ci + 1);
        // Consume all samples whose left column == xlo+ci (wave-uniform count).
        while (s < 14 && gn == ci) {
            float4 p = lerp4(va, vb, wx);
            if ((s & 1) == 0) {
                acc = p;
            } else {
                float4 r;
                r.x = (acc.x + p.x) * 0.25f;
                r.y = (acc.y + p.y) * 0.25f;
                r.z = (acc.z + p.z) * 0.25f;
                r.w = (acc.w + p.w) * 0.25f;
                outp[(s >> 1) << 6] = r;
            }
            ++s;
            xsf = basex + (float)s * stepx;
            gf = floorf(xsf);
            gn = __builtin_amdgcn_readfirstlane((int)gf) - xlo;
            wx = xsf - gf;
        }
        va = vb;
    }
}

__global__ __launch_bounds__(256) void roi_align_colmajor(
    const float* __restrict__ fm,
    const float* __restrict__ boxes,
    float* __restrict__ out)
{
    int bid = blockIdx.x;
    int newbid = (bid & 7) * 224 + (bid >> 3);   // XCD -> batch locality
    int t = threadIdx.x;
    int lane = t & 63;                           // channel float4 group
    int g = newbid * 4 + (t >> 6);               // wave id 0..7167 = (n, oy)
    int n = (int)(((unsigned)g * 9363u) >> 16);  // g / 7 (exact for g < 7168)
    int oy = g - n * 7;
    int b = n >> 7;

    // Box math — identical to all verified rounds.
    float bx0 = boxes[n * 4 + 0] * (1.0f / 31.0f);
    float by0 = boxes[n * 4 + 1] * (1.0f / 31.0f);
    float bx1 = boxes[n * 4 + 2] * (1.0f / 31.0f);
    float by1 = boxes[n * 4 + 3] * (1.0f / 31.0f);
    float x1 = fmaxf(bx0, 0.0f), y1 = fmaxf(by0, 0.0f);
    float x2 = fminf(bx1, 1.0f), y2 = fminf(by1, 1.0f);
    float bin_h = (y2 - y1) / 7.0f;
    float bin_w = (x2 - x1) / 7.0f;
    float gy1 = y1 + 0.25f * bin_h;
    float gx1 = x1 + 0.25f * bin_w;
    float gy2 = y2 - 0.25f * bin_h;
    float gx2 = x2 - 0.25f * bin_w;
    float basey = gy1 * 31.0f;
    float basex = gx1 * 31.0f;
    float stepy = (gy2 - gy1) * (31.0f / 13.0f);
    float stepx = (gx2 - gx1) * (31.0f / 13.0f);

    // Row geometry for this oy (fixed across all 14 x-samples).
    float ysf0 = basey + (float)(2 * oy) * stepy;
    float ysf1 = basey + (float)(2 * oy + 1) * stepy;
    float f0f = floorf(ysf0);
    float f1f = floorf(ysf1);
    float wy0 = ysf0 - f0f;
    float wy1 = ysf1 - f1f;
    int f0 = (int)f0f;                                        // >= 0, <= 30
    int dy = __builtin_amdgcn_readfirstlane((int)f1f - f0);   // 0, 1, or 2

    const float4* fm4 = (const float4*)fm;
    const float4* basep = fm4 + (size_t)b * (NH * NW * 64) + lane;
    int ro0 = (min(f0,     NH - 1) * NW) << 6;
    int ro1 = (min(f0 + 1, NH - 1) * NW) << 6;
    int ro2 = (min(f0 + 2, NH - 1) * NW) << 6;
    int ro3 = (min(f0 + 3, NH - 1) * NW) << 6;

    int xlo = __builtin_amdgcn_readfirstlane((int)floorf(basex));
    float4* outp = (float4*)out + (n * 49 + oy * 7) * 64 + lane;

    if (dy == 0)      roi_row_proc<0>(basep, ro0, ro1, ro2, ro3, xlo, basex, stepx, wy0, wy1, outp);
    else if (dy == 1) roi_row_proc<1>(basep, ro0, ro1, ro2, ro3, xlo, basex, stepx, wy0, wy1, outp);
    else              roi_row_proc<2>(basep, ro0, ro1, ro2, ro3, xlo, basex, stepx, wy0, wy1, outp);
}

extern "C" void kernel_launch(void* const* d_in, const int* in_sizes, int n_in,
                              void* d_out, int out_size, void* d_ws, size_t ws_size,
                              hipStream_t stream) {
    const float* fm    = (const float*)d_in[0];
    const float* boxes = (const float*)d_in[1];
    float* out = (float*)d_out;

    // 7168 waves = 1024 ROIs x 7 oy-rows; 4 waves/block -> 1792 blocks.
    roi_align_colmajor<<<1792, 256, 0, stream>>>(fm, boxes, out);
}